// Round 14
// baseline (442.858 us; speedup 1.0000x reference)
//
#include <hip/hip_runtime.h>
#include <hip/hip_bf16.h>

using f32x4 = __attribute__((ext_vector_type(4))) float;
using bf16x8 = __attribute__((ext_vector_type(8))) short;

#define DEVI __device__ __forceinline__

DEVI short f2bf(float f) { __hip_bfloat16 h = __float2bfloat16(f); return *reinterpret_cast<short*>(&h); }
DEVI unsigned int pk2(float a, float b) {
    float2 t; t.x = a; t.y = b;
    __hip_bfloat162 h = __float22bfloat162_rn(t);
    return *reinterpret_cast<unsigned int*>(&h);
}
DEVI float bf2f(unsigned short s) { unsigned int u = ((unsigned int)s) << 16; return __uint_as_float(u); }

DEVI void pl32swap(unsigned& a, unsigned& b) { asm("v_permlane32_swap_b32 %0, %1" : "+v"(a), "+v"(b)); }
DEVI void pl16swap(unsigned& a, unsigned& b) { asm("v_permlane16_swap_b32 %0, %1" : "+v"(a), "+v"(b)); }

constexpr int NB = 8192;
constexpr int NT = 49;
constexpr int CD = 128;
constexpr float SCALE = 0.17677669529663687f;
constexpr float LOG2E = 1.4426950408889634f;

// ---- ws layout (bytes) ----
constexpr size_t WS_QKVWT  = 0;        // 384*128 bf16 [n][k] plain transposed
constexpr size_t WS_PROJWT = 98304;    // 128*128 bf16 [n][k] plain transposed
constexpr size_t WS_BIAS   = 131072;   // 4*2401 bf16 transposed [h][k][q] x LOG2E

DEVI void div49(unsigned grow, unsigned& bI, unsigned& tI) {
    bI = (unsigned)(((unsigned long long)grow * 2804876602ull) >> 37);
    tI = grow - bI * 49u;
}

DEVI int swz128(int row, int col) { return row * 128 + (col ^ ((row & 7) << 3)); }

// ============================================================================
// prep: both weight matrices plain-transposed to [n][k] bf16;
// bias gathered transposed [h][k][q] x LOG2E.
// ============================================================================
__global__ __launch_bounds__(256) void prep_kernel(
    const float* __restrict__ qkv_w, const float* __restrict__ proj_w,
    const float* __restrict__ rbt, const int* __restrict__ rel_index,
    short* __restrict__ qkvwT, short* __restrict__ projwT, unsigned short* __restrict__ biasBf)
{
    int i = blockIdx.x * 256 + threadIdx.x;
    if (i < 384 * 128) {
        int n = i >> 7, j = i & 127;
        qkvwT[n * 128 + j] = f2bf(qkv_w[j * 384 + n]);
    }
    if (i < 128 * 128) {
        int n = i >> 7, j = i & 127;
        projwT[n * 128 + j] = f2bf(proj_w[j * 128 + n]);
    }
    if (i < 4 * NT * NT) {
        int h = i / (NT * NT); int t = i % (NT * NT);
        int k = t / NT, q = t - k * NT;
        biasBf[i] = (unsigned short)f2bf(rbt[rel_index[q * NT + k] * 4 + h] * LOG2E);
    }
}

// ============================================================================
// FUSED kernel: block = 1 window (512 thr, 8 waves). LDS 48 KB -> 3 blocks/CU.
//   qk planes [2][4 heads][64 tok][32 d] chunk-XOR ((d>>2) ^ (t&6))  32 KB
//   vS        [4][32 d][64 slots] slot-permuted + XOR                16 KB
//   mT (13 KB) aliases q-plane after P2a; oS (16 KB) aliases k-plane.
// P1: swapped-mfma QKV (weights direct from L2-hot global), b64 packed stores.
// P2: swapped-QK^T in-register softmax + permlane butterfly + PV.
// P3: deduped proj from oS.
// ============================================================================
__global__ __launch_bounds__(512, 6) void fused_kernel(
    const float* __restrict__ x, const float* __restrict__ mask,
    const float* __restrict__ qkv_b, const short* __restrict__ qkvwT,
    const unsigned short* __restrict__ biasT, const short* __restrict__ projwT,
    const float* __restrict__ proj_b, float* __restrict__ out)
{
    __shared__ __attribute__((aligned(16))) short pool[24576];   // 49152 B
    char*  qkb = (char*)pool;            // q plane [0,16384), k plane [16384,32768)
    char*  vSb = (char*)pool + 32768;    // 16384 B
    float* mT  = (float*)pool;           // aliases q plane (after P2a)
    short* oS  = pool + 8192;            // aliases k plane (after P2a)

    const int b = blockIdx.x;
    const int tid = threadIdx.x;
    const int w = tid >> 6, lane = tid & 63, lr = lane & 15, lg = lane >> 4;
    const int h = w >> 1, half = w & 1;
    const int wpair = w >> 1;            // n-tile selector 0..3
    const int tsel = w & 1;              // token-pair selector

    // ---- mask prefetch to regs (independent; hides under P1) ----
    const float* mb_ = mask + (size_t)b * (NT * NT);
    float mreg[5];
#pragma unroll
    for (int ii = 0; ii < 5; ++ii) {
        int i = tid + ii * 512;
        mreg[ii] = (i < NT * NT) ? mb_[i] * LOG2E : 0.f;
    }

    // ---- x fragments: wave covers token-tiles {2*tsel, 2*tsel+1} ----
    bf16x8 af[2][4];
#pragma unroll
    for (int mf = 0; mf < 2; ++mf) {
        const int row = 32 * tsel + 16 * mf + lr;
        const bool valid = row < NT;
        const float* xrow = x + ((size_t)b * NT + (valid ? row : 0)) * CD;
#pragma unroll
        for (int kt = 0; kt < 4; ++kt) {
            float4 v0 = {0.f,0.f,0.f,0.f}, v1 = {0.f,0.f,0.f,0.f};
            if (valid) {
                const float4* p = reinterpret_cast<const float4*>(xrow + kt * 32 + lg * 8);
                v0 = p[0]; v1 = p[1];
            }
            union { unsigned int u[4]; bf16x8 v; } cv;
            cv.u[0] = pk2(v0.x, v0.y); cv.u[1] = pk2(v0.z, v0.w);
            cv.u[2] = pk2(v1.x, v1.y); cv.u[3] = pk2(v1.z, v1.w);
            af[mf][kt] = cv.v;
        }
    }

    // ================= P1: QKV GEMM, weights direct from global =================
    // q/k: SWAPPED mfma(W, x) -> lane holds [token=lr][d=4lg+r] -> b64 store
#pragma unroll
    for (int c = 0; c < 2; ++c) {
#pragma unroll
        for (int nn = 0; nn < 2; ++nn) {
            const int ntl = wpair + 4 * nn;
            const int nt = c * 8 + ntl;
            const int hh = (ntl >> 1) & 3;
            const int dtile = ntl & 1;
            bf16x8 wf[4];
            const short* wr_ = qkvwT + (nt * 16 + lr) * 128 + lg * 8;
#pragma unroll
            for (int kt = 0; kt < 4; ++kt)
                wf[kt] = *reinterpret_cast<const bf16x8*>(wr_ + kt * 32);
            const float4 b4 = *reinterpret_cast<const float4*>(qkv_b + nt * 16 + 4 * lg);
            const float scl = (c == 0) ? SCALE * LOG2E : 1.0f;
#pragma unroll
            for (int tf = 0; tf < 2; ++tf) {
                f32x4 acc = {0.f, 0.f, 0.f, 0.f};
#pragma unroll
                for (int kt = 0; kt < 4; ++kt)
                    acc = __builtin_amdgcn_mfma_f32_16x16x32_bf16(wf[kt], af[tf][kt], acc, 0, 0, 0);
                const int t = 16 * (2 * tsel + tf) + lr;
                const int gp = (dtile * 4 + lg) ^ (t & 6);
                uint2 s;
                s.x = pk2((acc[0] + b4.x) * scl, (acc[1] + b4.y) * scl);
                s.y = pk2((acc[2] + b4.z) * scl, (acc[3] + b4.w) * scl);
                *reinterpret_cast<uint2*>(qkb + c * 16384 + hh * 4096 + t * 64 + gp * 8) = s;
            }
        }
    }
    // v: non-swapped mfma(x, W) -> lane holds [d=d0+lr][4 consecutive slot tokens] -> b64
#pragma unroll
    for (int nn = 0; nn < 2; ++nn) {
        const int ntl = wpair + 4 * nn;
        const int nt = 16 + ntl;
        const int hh = (ntl >> 1) & 3;
        const int d0 = (ntl & 1) * 16;
        bf16x8 wf[4];
        const short* wr_ = qkvwT + (nt * 16 + lr) * 128 + lg * 8;
#pragma unroll
        for (int kt = 0; kt < 4; ++kt)
            wf[kt] = *reinterpret_cast<const bf16x8*>(wr_ + kt * 32);
        const float bv = qkv_b[nt * 16 + lr];
        const int d = d0 + lr;
#pragma unroll
        for (int tf = 0; tf < 2; ++tf) {
            f32x4 acc = {0.f, 0.f, 0.f, 0.f};
#pragma unroll
            for (int kt = 0; kt < 4; ++kt)
                acc = __builtin_amdgcn_mfma_f32_16x16x32_bf16(af[tf][kt], wf[kt], acc, 0, 0, 0);
            const int tt = 2 * tsel + tf;
            // token = 16*tt + 4*lg + r ; slot = (bb<8) ? 8a+bb : 24+8a+bb, a=tt, bb=4lg+r
            const int slotq = (lg < 2) ? (tt * 8 + 4 * lg) : (24 + tt * 8 + 4 * lg);
            const int gp = (slotq >> 2) ^ ((d & 7) << 1);
            uint2 s;
            s.x = pk2(acc[0] + bv, acc[1] + bv);
            s.y = pk2(acc[2] + bv, acc[3] + bv);
            *reinterpret_cast<uint2*>(vSb + hh * 4096 + d * 128 + gp * 8) = s;
        }
    }
    __syncthreads();   // B1: q/k/v visible

    // ================= P2a: q/k fragment loads =================
    const int mt0 = 2 * half;
    bf16x8 qa[2], kb[4];
#pragma unroll
    for (int i = 0; i < 2; ++i) {
        const int t = 16 * (mt0 + i) + lr;
        qa[i] = *reinterpret_cast<const bf16x8*>(qkb + h * 4096 + t * 64 + ((16 * lg) ^ ((t & 6) << 3)));
    }
#pragma unroll
    for (int t4 = 0; t4 < 4; ++t4) {
        const int t = 16 * t4 + lr;
        kb[t4] = *reinterpret_cast<const bf16x8*>(qkb + 16384 + h * 4096 + t * 64 + ((16 * lg) ^ ((t & 6) << 3)));
    }
    __syncthreads();   // B2: all q/k reads done; planes become mT / oS

    // ---- scatter mask regs -> mT transposed (q plane region) ----
#pragma unroll
    for (int ii = 0; ii < 5; ++ii) {
        int i = tid + ii * 512;
        if (i < NT * NT) {
            unsigned q_, k_;
            div49((unsigned)i, q_, k_);
            mT[k_ * 65 + q_] = mreg[ii];
        }
    }
    __syncthreads();   // B3: mT ready

    // ================= P2b: attn =================
    const unsigned short* biasTh = biasT + h * (NT * NT);
    const short* vSs = (short*)vSb + h * 2048;
    const int sw8 = (lr & 7) << 3;

    f32x4 oacc[2][2];
#pragma unroll
    for (int mt2 = 0; mt2 < 2; ++mt2) { oacc[mt2][0] = f32x4{0,0,0,0}; oacc[mt2][1] = f32x4{0,0,0,0}; }

#pragma unroll
    for (int mt2 = 0; mt2 < 2; ++mt2) {
        const int qcol = 16 * (mt0 + mt2) + lr;

        float mbb[4][4];
#pragma unroll
        for (int ct = 0; ct < 4; ++ct)
#pragma unroll
            for (int r = 0; r < 4; ++r) {
                int k = 16 * ct + 4 * lg + r;
                int kc = min(k, 49);
                mbb[ct][r] = mT[kc * 65 + qcol] + bf2f(biasTh[kc * NT + qcol]);
            }

        f32x4 sacc[4];
#pragma unroll
        for (int ct = 0; ct < 4; ++ct) {
            f32x4 z = {0.f, 0.f, 0.f, 0.f};
            sacc[ct] = __builtin_amdgcn_mfma_f32_16x16x32_bf16(kb[ct], qa[mt2], z, 0, 0, 0);
        }

        float e[4][4];
        float psum = 0.f;
#pragma unroll
        for (int ct = 0; ct < 4; ++ct)
#pragma unroll
            for (int r = 0; r < 4; ++r) {
                float ee = exp2f(sacc[ct][r] + mbb[ct][r]);
                if (ct == 3) ee = (r == 0 && lg == 0) ? ee : 0.f;
                e[ct][r] = ee;
                psum += ee;
            }
        psum += __shfl_xor(psum, 16);
        psum += __shfl_xor(psum, 32);
        const float inv = 1.0f / psum;

        unsigned A0 = pk2(e[0][0] * inv, e[0][1] * inv);
        unsigned A1 = pk2(e[1][0] * inv, e[1][1] * inv);
        unsigned A2 = pk2(e[2][0] * inv, e[2][1] * inv);
        unsigned A3 = pk2(e[3][0] * inv, e[3][1] * inv);
        unsigned B0 = pk2(e[0][2] * inv, e[0][3] * inv);
        unsigned B1 = pk2(e[1][2] * inv, e[1][3] * inv);
        unsigned B2 = pk2(e[2][2] * inv, e[2][3] * inv);
        unsigned B3 = pk2(e[3][2] * inv, e[3][3] * inv);
        pl32swap(A0, A2); pl32swap(A1, A3);
        pl16swap(A0, A1); pl16swap(A2, A3);
        pl32swap(B0, B2); pl32swap(B1, B3);
        pl16swap(B0, B1); pl16swap(B2, B3);
        union { unsigned u[4]; bf16x8 v; } p0, p1;
        p0.u[0] = A0; p0.u[1] = B0; p0.u[2] = A1; p0.u[3] = B1;
        p1.u[0] = A2; p1.u[1] = B2; p1.u[2] = A3; p1.u[3] = B3;

#pragma unroll
        for (int nt = 0; nt < 2; ++nt) {
            bf16x8 vb0 = *reinterpret_cast<const bf16x8*>(&vSs[(16 * nt + lr) * 64 + ((8 * lg) ^ sw8)]);
            bf16x8 vb1 = *reinterpret_cast<const bf16x8*>(&vSs[(16 * nt + lr) * 64 + ((32 + 8 * lg) ^ sw8)]);
            oacc[mt2][nt] = __builtin_amdgcn_mfma_f32_16x16x32_bf16(p0.v, vb0, oacc[mt2][nt], 0, 0, 0);
            oacc[mt2][nt] = __builtin_amdgcn_mfma_f32_16x16x32_bf16(p1.v, vb1, oacc[mt2][nt], 0, 0, 0);
        }
    }

    // ---- write o tile into k-plane region (dead after B2) ----
#pragma unroll
    for (int mt2 = 0; mt2 < 2; ++mt2)
#pragma unroll
        for (int nt = 0; nt < 2; ++nt)
#pragma unroll
            for (int r = 0; r < 4; ++r) {
                int row = 16 * (mt0 + mt2) + 4 * lg + r;
                int col = 32 * h + 16 * nt + lr;
                oS[swz128(row, col)] = f2bf(oacc[mt2][nt][r]);
            }
    __syncthreads();   // B4: o ready

    // ================= P3: proj (wave w -> col-tile w) =================
    {
        bf16x8 bbf[4];
        const short* brow = projwT + (w * 16 + lr) * 128 + lg * 8;
#pragma unroll
        for (int kt = 0; kt < 4; ++kt)
            bbf[kt] = *reinterpret_cast<const bf16x8*>(brow + kt * 32);

        f32x4 acc[4];
#pragma unroll
        for (int mf = 0; mf < 4; ++mf) acc[mf] = f32x4{0.f, 0.f, 0.f, 0.f};

#pragma unroll
        for (int mf = 0; mf < 4; ++mf)
#pragma unroll
            for (int kt = 0; kt < 4; ++kt) {
                bf16x8 a2 = *reinterpret_cast<const bf16x8*>(&oS[swz128(16 * mf + lr, kt * 32 + lg * 8)]);
                acc[mf] = __builtin_amdgcn_mfma_f32_16x16x32_bf16(a2, bbf[kt], acc[mf], 0, 0, 0);
            }

        const int col = w * 16 + lr;
        const float pb = proj_b[col];
#pragma unroll
        for (int mf = 0; mf < 4; ++mf)
#pragma unroll
            for (int r = 0; r < 4; ++r) {
                int row = 16 * mf + 4 * lg + r;
                if (row < NT)
                    out[((size_t)b * NT + row) * CD + col] = acc[mf][r] + pb;
            }
    }
}

extern "C" void kernel_launch(void* const* d_in, const int* in_sizes, int n_in,
                              void* d_out, int out_size, void* d_ws, size_t ws_size,
                              hipStream_t stream) {
    const float* x      = (const float*)d_in[0];
    const float* mask   = (const float*)d_in[1];
    const float* qkv_w  = (const float*)d_in[2];
    const float* qkv_b  = (const float*)d_in[3];
    const float* rbt    = (const float*)d_in[4];
    const float* proj_w = (const float*)d_in[5];
    const float* proj_b = (const float*)d_in[6];
    const int*   ridx   = (const int*)d_in[7];
    float* out = (float*)d_out;

    char* ws = (char*)d_ws;
    short* qkvwT  = (short*)(ws + WS_QKVWT);
    short* projwT = (short*)(ws + WS_PROJWT);
    unsigned short* biasBf = (unsigned short*)(ws + WS_BIAS);

    prep_kernel<<<192, 256, 0, stream>>>(qkv_w, proj_w, rbt, ridx, qkvwT, projwT, biasBf);
    fused_kernel<<<NB, 512, 0, stream>>>(x, mask, qkv_b, qkvwT, biasBf, projwT, proj_b, out);
}

// Round 15
// 366.117 us; speedup vs baseline: 1.2096x; 1.2096x over previous
//
#include <hip/hip_runtime.h>
#include <hip/hip_bf16.h>

using f32x4 = __attribute__((ext_vector_type(4))) float;
using bf16x8 = __attribute__((ext_vector_type(8))) short;

#define DEVI __device__ __forceinline__

DEVI short f2bf(float f) { __hip_bfloat16 h = __float2bfloat16(f); return *reinterpret_cast<short*>(&h); }
DEVI unsigned int pk2(float a, float b) {
    float2 t; t.x = a; t.y = b;
    __hip_bfloat162 h = __float22bfloat162_rn(t);
    return *reinterpret_cast<unsigned int*>(&h);
}
DEVI float bf2f(unsigned short s) { unsigned int u = ((unsigned int)s) << 16; return __uint_as_float(u); }

DEVI void pl32swap(unsigned& a, unsigned& b) { asm("v_permlane32_swap_b32 %0, %1" : "+v"(a), "+v"(b)); }
DEVI void pl16swap(unsigned& a, unsigned& b) { asm("v_permlane16_swap_b32 %0, %1" : "+v"(a), "+v"(b)); }

constexpr int NB = 8192;
constexpr int NT = 49;
constexpr int CD = 128;
constexpr float SCALE = 0.17677669529663687f;
constexpr float LOG2E = 1.4426950408889634f;

// ---- ws layout (bytes) ----
constexpr size_t WS_QKVWT  = 0;        // 384*128 bf16 [n][k] plain transposed
constexpr size_t WS_PROJWT = 98304;    // 128*128 bf16 [n][k] plain transposed
constexpr size_t WS_BIAS   = 131072;   // 4*2401 bf16 transposed [h][k][q] x LOG2E

DEVI void div49(unsigned grow, unsigned& bI, unsigned& tI) {
    bI = (unsigned)(((unsigned long long)grow * 2804876602ull) >> 37);
    tI = grow - bI * 49u;
}

DEVI int swz128(int row, int col) { return row * 128 + (col ^ ((row & 7) << 3)); }

// ============================================================================
// prep: both weight matrices plain-transposed to [n][k] bf16;
// bias gathered transposed [h][k][q] x LOG2E.
// ============================================================================
__global__ __launch_bounds__(256) void prep_kernel(
    const float* __restrict__ qkv_w, const float* __restrict__ proj_w,
    const float* __restrict__ rbt, const int* __restrict__ rel_index,
    short* __restrict__ qkvwT, short* __restrict__ projwT, unsigned short* __restrict__ biasBf)
{
    int i = blockIdx.x * 256 + threadIdx.x;
    if (i < 384 * 128) {
        int n = i >> 7, j = i & 127;
        qkvwT[n * 128 + j] = f2bf(qkv_w[j * 384 + n]);
    }
    if (i < 128 * 128) {
        int n = i >> 7, j = i & 127;
        projwT[n * 128 + j] = f2bf(proj_w[j * 128 + n]);
    }
    if (i < 4 * NT * NT) {
        int h = i / (NT * NT); int t = i % (NT * NT);
        int k = t / NT, q = t - k * NT;
        biasBf[i] = (unsigned short)f2bf(rbt[rel_index[q * NT + k] * 4 + h] * LOG2E);
    }
}

// ============================================================================
// FUSED kernel: block = 1 window (512 thr, 8 waves). LDS 48 KB.
//   qk planes [2][4 heads][64 tok][32 d] chunk-XOR ((d>>2) ^ (t&6))  32 KB
//   vS        [4][32 d][64 slots] slot-permuted + XOR                16 KB
//   mT (13 KB) aliases q-plane after P2a; oS (16 KB) aliases k-plane.
// P1: swapped-mfma QKV (weights direct from L2-hot global), b64 packed stores.
// P2: swapped-QK^T in-register softmax + permlane butterfly + PV.
// P3: deduped proj from oS.
// launch_bounds (512,4): R14's (512,6) forced VGPR->40 with ~80B/thread
// scratch spills (WRITE 547MB). Natural allocation ~64-80 VGPR, no spill;
// if <=64, the 48KB LDS still admits 3 blocks/CU at runtime.
// ============================================================================
__global__ __launch_bounds__(512, 4) void fused_kernel(
    const float* __restrict__ x, const float* __restrict__ mask,
    const float* __restrict__ qkv_b, const short* __restrict__ qkvwT,
    const unsigned short* __restrict__ biasT, const short* __restrict__ projwT,
    const float* __restrict__ proj_b, float* __restrict__ out)
{
    __shared__ __attribute__((aligned(16))) short pool[24576];   // 49152 B
    char*  qkb = (char*)pool;            // q plane [0,16384), k plane [16384,32768)
    char*  vSb = (char*)pool + 32768;    // 16384 B
    float* mT  = (float*)pool;           // aliases q plane (after P2a)
    short* oS  = pool + 8192;            // aliases k plane (after P2a)

    const int b = blockIdx.x;
    const int tid = threadIdx.x;
    const int w = tid >> 6, lane = tid & 63, lr = lane & 15, lg = lane >> 4;
    const int h = w >> 1, half = w & 1;
    const int wpair = w >> 1;            // n-tile selector 0..3
    const int tsel = w & 1;              // token-pair selector

    // ---- mask prefetch to regs (independent; hides under P1) ----
    const float* mb_ = mask + (size_t)b * (NT * NT);
    float mreg[5];
#pragma unroll
    for (int ii = 0; ii < 5; ++ii) {
        int i = tid + ii * 512;
        mreg[ii] = (i < NT * NT) ? mb_[i] * LOG2E : 0.f;
    }

    // ---- x fragments: wave covers token-tiles {2*tsel, 2*tsel+1} ----
    bf16x8 af[2][4];
#pragma unroll
    for (int mf = 0; mf < 2; ++mf) {
        const int row = 32 * tsel + 16 * mf + lr;
        const bool valid = row < NT;
        const float* xrow = x + ((size_t)b * NT + (valid ? row : 0)) * CD;
#pragma unroll
        for (int kt = 0; kt < 4; ++kt) {
            float4 v0 = {0.f,0.f,0.f,0.f}, v1 = {0.f,0.f,0.f,0.f};
            if (valid) {
                const float4* p = reinterpret_cast<const float4*>(xrow + kt * 32 + lg * 8);
                v0 = p[0]; v1 = p[1];
            }
            union { unsigned int u[4]; bf16x8 v; } cv;
            cv.u[0] = pk2(v0.x, v0.y); cv.u[1] = pk2(v0.z, v0.w);
            cv.u[2] = pk2(v1.x, v1.y); cv.u[3] = pk2(v1.z, v1.w);
            af[mf][kt] = cv.v;
        }
    }

    // ================= P1: QKV GEMM, weights direct from global =================
    // q/k: SWAPPED mfma(W, x) -> lane holds [token=lr][d=4lg+r] -> b64 store
#pragma unroll
    for (int c = 0; c < 2; ++c) {
#pragma unroll
        for (int nn = 0; nn < 2; ++nn) {
            const int ntl = wpair + 4 * nn;
            const int nt = c * 8 + ntl;
            const int hh = (ntl >> 1) & 3;
            const int dtile = ntl & 1;
            bf16x8 wf[4];
            const short* wr_ = qkvwT + (nt * 16 + lr) * 128 + lg * 8;
#pragma unroll
            for (int kt = 0; kt < 4; ++kt)
                wf[kt] = *reinterpret_cast<const bf16x8*>(wr_ + kt * 32);
            const float4 b4 = *reinterpret_cast<const float4*>(qkv_b + nt * 16 + 4 * lg);
            const float scl = (c == 0) ? SCALE * LOG2E : 1.0f;
#pragma unroll
            for (int tf = 0; tf < 2; ++tf) {
                f32x4 acc = {0.f, 0.f, 0.f, 0.f};
#pragma unroll
                for (int kt = 0; kt < 4; ++kt)
                    acc = __builtin_amdgcn_mfma_f32_16x16x32_bf16(wf[kt], af[tf][kt], acc, 0, 0, 0);
                const int t = 16 * (2 * tsel + tf) + lr;
                const int gp = (dtile * 4 + lg) ^ (t & 6);
                uint2 s;
                s.x = pk2((acc[0] + b4.x) * scl, (acc[1] + b4.y) * scl);
                s.y = pk2((acc[2] + b4.z) * scl, (acc[3] + b4.w) * scl);
                *reinterpret_cast<uint2*>(qkb + c * 16384 + hh * 4096 + t * 64 + gp * 8) = s;
            }
        }
    }
    // v: non-swapped mfma(x, W) -> lane holds [d=d0+lr][4 consecutive slot tokens] -> b64
#pragma unroll
    for (int nn = 0; nn < 2; ++nn) {
        const int ntl = wpair + 4 * nn;
        const int nt = 16 + ntl;
        const int hh = (ntl >> 1) & 3;
        const int d0 = (ntl & 1) * 16;
        bf16x8 wf[4];
        const short* wr_ = qkvwT + (nt * 16 + lr) * 128 + lg * 8;
#pragma unroll
        for (int kt = 0; kt < 4; ++kt)
            wf[kt] = *reinterpret_cast<const bf16x8*>(wr_ + kt * 32);
        const float bv = qkv_b[nt * 16 + lr];
        const int d = d0 + lr;
#pragma unroll
        for (int tf = 0; tf < 2; ++tf) {
            f32x4 acc = {0.f, 0.f, 0.f, 0.f};
#pragma unroll
            for (int kt = 0; kt < 4; ++kt)
                acc = __builtin_amdgcn_mfma_f32_16x16x32_bf16(af[tf][kt], wf[kt], acc, 0, 0, 0);
            const int tt = 2 * tsel + tf;
            // token = 16*tt + 4*lg + r ; slot = (bb<8) ? 8a+bb : 24+8a+bb, a=tt, bb=4lg+r
            const int slotq = (lg < 2) ? (tt * 8 + 4 * lg) : (24 + tt * 8 + 4 * lg);
            const int gp = (slotq >> 2) ^ ((d & 7) << 1);
            uint2 s;
            s.x = pk2(acc[0] + bv, acc[1] + bv);
            s.y = pk2(acc[2] + bv, acc[3] + bv);
            *reinterpret_cast<uint2*>(vSb + hh * 4096 + d * 128 + gp * 8) = s;
        }
    }
    __syncthreads();   // B1: q/k/v visible

    // ================= P2a: q/k fragment loads =================
    const int mt0 = 2 * half;
    bf16x8 qa[2], kb[4];
#pragma unroll
    for (int i = 0; i < 2; ++i) {
        const int t = 16 * (mt0 + i) + lr;
        qa[i] = *reinterpret_cast<const bf16x8*>(qkb + h * 4096 + t * 64 + ((16 * lg) ^ ((t & 6) << 3)));
    }
#pragma unroll
    for (int t4 = 0; t4 < 4; ++t4) {
        const int t = 16 * t4 + lr;
        kb[t4] = *reinterpret_cast<const bf16x8*>(qkb + 16384 + h * 4096 + t * 64 + ((16 * lg) ^ ((t & 6) << 3)));
    }
    __syncthreads();   // B2: all q/k reads done; planes become mT / oS

    // ---- scatter mask regs -> mT transposed (q plane region) ----
#pragma unroll
    for (int ii = 0; ii < 5; ++ii) {
        int i = tid + ii * 512;
        if (i < NT * NT) {
            unsigned q_, k_;
            div49((unsigned)i, q_, k_);
            mT[k_ * 65 + q_] = mreg[ii];
        }
    }
    __syncthreads();   // B3: mT ready

    // ================= P2b: attn =================
    const unsigned short* biasTh = biasT + h * (NT * NT);
    const short* vSs = (short*)vSb + h * 2048;
    const int sw8 = (lr & 7) << 3;

    f32x4 oacc[2][2];
#pragma unroll
    for (int mt2 = 0; mt2 < 2; ++mt2) { oacc[mt2][0] = f32x4{0,0,0,0}; oacc[mt2][1] = f32x4{0,0,0,0}; }

#pragma unroll
    for (int mt2 = 0; mt2 < 2; ++mt2) {
        const int qcol = 16 * (mt0 + mt2) + lr;

        float mbb[4][4];
#pragma unroll
        for (int ct = 0; ct < 4; ++ct)
#pragma unroll
            for (int r = 0; r < 4; ++r) {
                int k = 16 * ct + 4 * lg + r;
                int kc = min(k, 49);
                mbb[ct][r] = mT[kc * 65 + qcol] + bf2f(biasTh[kc * NT + qcol]);
            }

        f32x4 sacc[4];
#pragma unroll
        for (int ct = 0; ct < 4; ++ct) {
            f32x4 z = {0.f, 0.f, 0.f, 0.f};
            sacc[ct] = __builtin_amdgcn_mfma_f32_16x16x32_bf16(kb[ct], qa[mt2], z, 0, 0, 0);
        }

        float e[4][4];
        float psum = 0.f;
#pragma unroll
        for (int ct = 0; ct < 4; ++ct)
#pragma unroll
            for (int r = 0; r < 4; ++r) {
                float ee = exp2f(sacc[ct][r] + mbb[ct][r]);
                if (ct == 3) ee = (r == 0 && lg == 0) ? ee : 0.f;
                e[ct][r] = ee;
                psum += ee;
            }
        psum += __shfl_xor(psum, 16);
        psum += __shfl_xor(psum, 32);
        const float inv = 1.0f / psum;

        unsigned A0 = pk2(e[0][0] * inv, e[0][1] * inv);
        unsigned A1 = pk2(e[1][0] * inv, e[1][1] * inv);
        unsigned A2 = pk2(e[2][0] * inv, e[2][1] * inv);
        unsigned A3 = pk2(e[3][0] * inv, e[3][1] * inv);
        unsigned B0 = pk2(e[0][2] * inv, e[0][3] * inv);
        unsigned B1 = pk2(e[1][2] * inv, e[1][3] * inv);
        unsigned B2 = pk2(e[2][2] * inv, e[2][3] * inv);
        unsigned B3 = pk2(e[3][2] * inv, e[3][3] * inv);
        pl32swap(A0, A2); pl32swap(A1, A3);
        pl16swap(A0, A1); pl16swap(A2, A3);
        pl32swap(B0, B2); pl32swap(B1, B3);
        pl16swap(B0, B1); pl16swap(B2, B3);
        union { unsigned u[4]; bf16x8 v; } p0, p1;
        p0.u[0] = A0; p0.u[1] = B0; p0.u[2] = A1; p0.u[3] = B1;
        p1.u[0] = A2; p1.u[1] = B2; p1.u[2] = A3; p1.u[3] = B3;

#pragma unroll
        for (int nt = 0; nt < 2; ++nt) {
            bf16x8 vb0 = *reinterpret_cast<const bf16x8*>(&vSs[(16 * nt + lr) * 64 + ((8 * lg) ^ sw8)]);
            bf16x8 vb1 = *reinterpret_cast<const bf16x8*>(&vSs[(16 * nt + lr) * 64 + ((32 + 8 * lg) ^ sw8)]);
            oacc[mt2][nt] = __builtin_amdgcn_mfma_f32_16x16x32_bf16(p0.v, vb0, oacc[mt2][nt], 0, 0, 0);
            oacc[mt2][nt] = __builtin_amdgcn_mfma_f32_16x16x32_bf16(p1.v, vb1, oacc[mt2][nt], 0, 0, 0);
        }
    }

    // ---- write o tile into k-plane region (dead after B2) ----
#pragma unroll
    for (int mt2 = 0; mt2 < 2; ++mt2)
#pragma unroll
        for (int nt = 0; nt < 2; ++nt)
#pragma unroll
            for (int r = 0; r < 4; ++r) {
                int row = 16 * (mt0 + mt2) + 4 * lg + r;
                int col = 32 * h + 16 * nt + lr;
                oS[swz128(row, col)] = f2bf(oacc[mt2][nt][r]);
            }
    __syncthreads();   // B4: o ready

    // ================= P3: proj (wave w -> col-tile w) =================
    {
        bf16x8 bbf[4];
        const short* brow = projwT + (w * 16 + lr) * 128 + lg * 8;
#pragma unroll
        for (int kt = 0; kt < 4; ++kt)
            bbf[kt] = *reinterpret_cast<const bf16x8*>(brow + kt * 32);

        f32x4 acc[4];
#pragma unroll
        for (int mf = 0; mf < 4; ++mf) acc[mf] = f32x4{0.f, 0.f, 0.f, 0.f};

#pragma unroll
        for (int mf = 0; mf < 4; ++mf)
#pragma unroll
            for (int kt = 0; kt < 4; ++kt) {
                bf16x8 a2 = *reinterpret_cast<const bf16x8*>(&oS[swz128(16 * mf + lr, kt * 32 + lg * 8)]);
                acc[mf] = __builtin_amdgcn_mfma_f32_16x16x32_bf16(a2, bbf[kt], acc[mf], 0, 0, 0);
            }

        const int col = w * 16 + lr;
        const float pb = proj_b[col];
#pragma unroll
        for (int mf = 0; mf < 4; ++mf)
#pragma unroll
            for (int r = 0; r < 4; ++r) {
                int row = 16 * mf + 4 * lg + r;
                if (row < NT)
                    out[((size_t)b * NT + row) * CD + col] = acc[mf][r] + pb;
            }
    }
}

extern "C" void kernel_launch(void* const* d_in, const int* in_sizes, int n_in,
                              void* d_out, int out_size, void* d_ws, size_t ws_size,
                              hipStream_t stream) {
    const float* x      = (const float*)d_in[0];
    const float* mask   = (const float*)d_in[1];
    const float* qkv_w  = (const float*)d_in[2];
    const float* qkv_b  = (const float*)d_in[3];
    const float* rbt    = (const float*)d_in[4];
    const float* proj_w = (const float*)d_in[5];
    const float* proj_b = (const float*)d_in[6];
    const int*   ridx   = (const int*)d_in[7];
    float* out = (float*)d_out;

    char* ws = (char*)d_ws;
    short* qkvwT  = (short*)(ws + WS_QKVWT);
    short* projwT = (short*)(ws + WS_PROJWT);
    unsigned short* biasBf = (unsigned short*)(ws + WS_BIAS);

    prep_kernel<<<192, 256, 0, stream>>>(qkv_w, proj_w, rbt, ridx, qkvwT, projwT, biasBf);
    fused_kernel<<<NB, 512, 0, stream>>>(x, mask, qkv_b, qkvwT, biasBf, projwT, proj_b, out);
}

// Round 16
// 292.626 us; speedup vs baseline: 1.5134x; 1.2511x over previous
//
#include <hip/hip_runtime.h>
#include <hip/hip_bf16.h>

using f32x4 = __attribute__((ext_vector_type(4))) float;
using bf16x8 = __attribute__((ext_vector_type(8))) short;

#define DEVI __device__ __forceinline__

DEVI short f2bf(float f) { __hip_bfloat16 h = __float2bfloat16(f); return *reinterpret_cast<short*>(&h); }
DEVI unsigned int pk2(float a, float b) {
    float2 t; t.x = a; t.y = b;
    __hip_bfloat162 h = __float22bfloat162_rn(t);
    return *reinterpret_cast<unsigned int*>(&h);
}
DEVI float bf2f(unsigned short s) { unsigned int u = ((unsigned int)s) << 16; return __uint_as_float(u); }

DEVI void pl32swap(unsigned& a, unsigned& b) { asm("v_permlane32_swap_b32 %0, %1" : "+v"(a), "+v"(b)); }
DEVI void pl16swap(unsigned& a, unsigned& b) { asm("v_permlane16_swap_b32 %0, %1" : "+v"(a), "+v"(b)); }

#define GLOAD_LDS16(gp, lp) \
    __builtin_amdgcn_global_load_lds((const __attribute__((address_space(1))) void*)(gp), \
                                     (__attribute__((address_space(3))) void*)(lp), 16, 0, 0)

constexpr int NB = 8192;
constexpr int NT = 49;
constexpr int CD = 128;
constexpr float SCALE = 0.17677669529663687f;
constexpr float LOG2E = 1.4426950408889634f;

// ---- ws layout (bytes) ----
constexpr size_t WS_QKVWS  = 0;        // 384*128 bf16, chunked + pre-swizzled
constexpr size_t WS_PROJWT = 98304;    // 128*128 bf16 [n][k] plain transposed
constexpr size_t WS_BIAS   = 131072;   // 4*2401 bf16 transposed [h][k][q] x LOG2E

DEVI void div49(unsigned grow, unsigned& bI, unsigned& tI) {
    bI = (unsigned)(((unsigned long long)grow * 2804876602ull) >> 37);
    tI = grow - bI * 49u;
}

DEVI int swz128(int row, int col) { return row * 128 + (col ^ ((row & 7) << 3)); }

// ============================================================================
// prep: qkv weights chunked [c][r][j^((r&7)<<3)] pre-swizzled (for gload_lds
// + XOR ds_read); proj weights plain-transposed; bias [h][k][q] x LOG2E.
// ============================================================================
__global__ __launch_bounds__(256) void prep_kernel(
    const float* __restrict__ qkv_w, const float* __restrict__ proj_w,
    const float* __restrict__ rbt, const int* __restrict__ rel_index,
    short* __restrict__ qkvwS, short* __restrict__ projwT, unsigned short* __restrict__ biasBf)
{
    int i = blockIdx.x * 256 + threadIdx.x;
    if (i < 384 * 128) {
        int n = i >> 7, j = i & 127;          // B[n][k=j]
        int c = n >> 7, r = n & 127;
        qkvwS[c * 16384 + r * 128 + (j ^ ((r & 7) << 3))] = f2bf(qkv_w[j * 384 + n]);
    }
    if (i < 128 * 128) {
        int n = i >> 7, j = i & 127;
        projwT[n * 128 + j] = f2bf(proj_w[j * 128 + n]);
    }
    if (i < 4 * NT * NT) {
        int h = i / (NT * NT); int t = i % (NT * NT);
        int k = t / NT, q = t - k * NT;
        biasBf[i] = (unsigned short)f2bf(rbt[rel_index[q * NT + k] * 4 + h] * LOG2E);
    }
}

// ============================================================================
// FUSED kernel: block = 1 window (512 thr, 8 waves). LDS 80 KB.
//   Wc  [0,32768)        weight chunk, DMA-staged; mT aliases after P1
//   qk  [32768,65536)    q plane then k plane, [4 h][64 t][32 d] chunk-XOR
//   vS  [65536,81920)    [4 h][32 d][64 slots] slot-permuted + XOR
//   oS aliases k-plane after B2.
// P1: weights DMA->LDS per chunk (R12), swapped-mfma QKV, packed b64 stores (R15).
// P2: swapped-QK^T in-register softmax + permlane butterfly + PV.
// P3: deduped proj from oS.
// ============================================================================
__global__ __launch_bounds__(512, 4) void fused_kernel(
    const float* __restrict__ x, const float* __restrict__ mask,
    const float* __restrict__ qkv_b, const short* __restrict__ qkvwS,
    const unsigned short* __restrict__ biasT, const short* __restrict__ projwT,
    const float* __restrict__ proj_b, float* __restrict__ out)
{
    __shared__ __attribute__((aligned(16))) short pool[40960];   // 81920 B
    char*  Wcb = (char*)pool;                  // [0, 32768)
    char*  qkb = (char*)pool + 32768;          // q [32768,49152), k [49152,65536)
    char*  vSb = (char*)pool + 65536;          // [65536, 81920)
    float* mT  = (float*)pool;                 // aliases Wc (after P1)
    short* oS  = (short*)((char*)pool + 49152);// aliases k plane (after B2)

    const int b = blockIdx.x;
    const int tid = threadIdx.x;
    const int w = tid >> 6, lane = tid & 63, lr = lane & 15, lg = lane >> 4;
    const int h = w >> 1, half = w & 1;
    const int wpair = w >> 1;            // n-tile selector 0..3
    const int tsel = w & 1;              // token-pair selector

    // ---- mask prefetch to regs (independent; hides under P1) ----
    const float* mb_ = mask + (size_t)b * (NT * NT);
    float mreg[5];
#pragma unroll
    for (int ii = 0; ii < 5; ++ii) {
        int i = tid + ii * 512;
        mreg[ii] = (i < NT * NT) ? mb_[i] * LOG2E : 0.f;
    }

    // ---- x fragments: wave covers token-tiles {2*tsel, 2*tsel+1} ----
    bf16x8 af[2][4];
#pragma unroll
    for (int mf = 0; mf < 2; ++mf) {
        const int row = 32 * tsel + 16 * mf + lr;
        const bool valid = row < NT;
        const float* xrow = x + ((size_t)b * NT + (valid ? row : 0)) * CD;
#pragma unroll
        for (int kt = 0; kt < 4; ++kt) {
            float4 v0 = {0.f,0.f,0.f,0.f}, v1 = {0.f,0.f,0.f,0.f};
            if (valid) {
                const float4* p = reinterpret_cast<const float4*>(xrow + kt * 32 + lg * 8);
                v0 = p[0]; v1 = p[1];
            }
            union { unsigned int u[4]; bf16x8 v; } cv;
            cv.u[0] = pk2(v0.x, v0.y); cv.u[1] = pk2(v0.z, v0.w);
            cv.u[2] = pk2(v1.x, v1.y); cv.u[3] = pk2(v1.z, v1.w);
            af[mf][kt] = cv.v;
        }
    }

    // ================= P1: QKV GEMM, weights DMA-staged per chunk =================
    const char* srcW = (const char*)qkvwS;
#pragma unroll
    for (int c = 0; c < 3; ++c) {
        // stage chunk c (32KB): 8 waves x 4 x 1KB
#pragma unroll
        for (int i = 0; i < 4; ++i)
            GLOAD_LDS16(srcW + c * 32768 + w * 4096 + i * 1024 + lane * 16,
                        Wcb + w * 4096 + i * 1024);
        __syncthreads();

        if (c < 2) {
            // q (c=0) / k (c=1): SWAPPED mfma(W, x) -> [token=lr][d=4lg+r] -> b64
#pragma unroll
            for (int nn = 0; nn < 2; ++nn) {
                const int ntl = wpair + 4 * nn;
                const int nt = c * 8 + ntl;
                const int hh = (ntl >> 1) & 3;
                const int dtile = ntl & 1;
                const float4 b4 = *reinterpret_cast<const float4*>(qkv_b + nt * 16 + 4 * lg);
                const float scl = (c == 0) ? SCALE * LOG2E : 1.0f;
                const char* wbase = Wcb + (ntl * 16 + lr) * 256;
                const int wsw = (lr & 7) << 4;
#pragma unroll
                for (int tf = 0; tf < 2; ++tf) {
                    f32x4 acc = {0.f, 0.f, 0.f, 0.f};
#pragma unroll
                    for (int kt = 0; kt < 4; ++kt) {
                        bf16x8 wf = *reinterpret_cast<const bf16x8*>(wbase + ((kt * 64 + lg * 16) ^ wsw));
                        acc = __builtin_amdgcn_mfma_f32_16x16x32_bf16(wf, af[tf][kt], acc, 0, 0, 0);
                    }
                    const int t = 16 * (2 * tsel + tf) + lr;
                    const int gp = (dtile * 4 + lg) ^ (t & 6);
                    uint2 s;
                    s.x = pk2((acc[0] + b4.x) * scl, (acc[1] + b4.y) * scl);
                    s.y = pk2((acc[2] + b4.z) * scl, (acc[3] + b4.w) * scl);
                    *reinterpret_cast<uint2*>(qkb + c * 16384 + hh * 4096 + t * 64 + gp * 8) = s;
                }
            }
        } else {
            // v: non-swapped mfma(x, W) -> [d=d0+lr][4 consecutive slot tokens] -> b64
#pragma unroll
            for (int nn = 0; nn < 2; ++nn) {
                const int ntl = wpair + 4 * nn;
                const int nt = 16 + ntl;
                const int hh = (ntl >> 1) & 3;
                const int d0 = (ntl & 1) * 16;
                const float bv = qkv_b[nt * 16 + lr];
                const int d = d0 + lr;
                const char* wbase = Wcb + (ntl * 16 + lr) * 256;
                const int wsw = (lr & 7) << 4;
#pragma unroll
                for (int tf = 0; tf < 2; ++tf) {
                    f32x4 acc = {0.f, 0.f, 0.f, 0.f};
#pragma unroll
                    for (int kt = 0; kt < 4; ++kt) {
                        bf16x8 wf = *reinterpret_cast<const bf16x8*>(wbase + ((kt * 64 + lg * 16) ^ wsw));
                        acc = __builtin_amdgcn_mfma_f32_16x16x32_bf16(af[tf][kt], wf, acc, 0, 0, 0);
                    }
                    const int tt = 2 * tsel + tf;
                    const int slotq = (lg < 2) ? (tt * 8 + 4 * lg) : (24 + tt * 8 + 4 * lg);
                    const int gp = (slotq >> 2) ^ ((d & 7) << 1);
                    uint2 s;
                    s.x = pk2(acc[0] + bv, acc[1] + bv);
                    s.y = pk2(acc[2] + bv, acc[3] + bv);
                    *reinterpret_cast<uint2*>(vSb + hh * 4096 + d * 128 + gp * 8) = s;
                }
            }
        }
        __syncthreads();   // chunk reads done before restage; c==2: B1 (q/k/v visible, Wc dead)
    }

    // ================= P2a: q/k fragment loads + mask scatter (disjoint) ========
    const int mt0 = 2 * half;
    bf16x8 qa[2], kb[4];
#pragma unroll
    for (int i = 0; i < 2; ++i) {
        const int t = 16 * (mt0 + i) + lr;
        qa[i] = *reinterpret_cast<const bf16x8*>(qkb + h * 4096 + t * 64 + ((16 * lg) ^ ((t & 6) << 3)));
    }
#pragma unroll
    for (int t4 = 0; t4 < 4; ++t4) {
        const int t = 16 * t4 + lr;
        kb[t4] = *reinterpret_cast<const bf16x8*>(qkb + 16384 + h * 4096 + t * 64 + ((16 * lg) ^ ((t & 6) << 3)));
    }
    // scatter mask regs -> mT transposed (Wc region, dead after B1)
#pragma unroll
    for (int ii = 0; ii < 5; ++ii) {
        int i = tid + ii * 512;
        if (i < NT * NT) {
            unsigned q_, k_;
            div49((unsigned)i, q_, k_);
            mT[k_ * 65 + q_] = mreg[ii];
        }
    }
    __syncthreads();   // B2: mT visible; all q/k frag reads done (k plane -> oS)

    // ================= P2b: attn =================
    const unsigned short* biasTh = biasT + h * (NT * NT);
    const short* vSs = (short*)vSb + h * 2048;
    const int sw8 = (lr & 7) << 3;

    f32x4 oacc[2][2];
#pragma unroll
    for (int mt2 = 0; mt2 < 2; ++mt2) { oacc[mt2][0] = f32x4{0,0,0,0}; oacc[mt2][1] = f32x4{0,0,0,0}; }

#pragma unroll
    for (int mt2 = 0; mt2 < 2; ++mt2) {
        const int qcol = 16 * (mt0 + mt2) + lr;

        float mbb[4][4];
#pragma unroll
        for (int ct = 0; ct < 4; ++ct)
#pragma unroll
            for (int r = 0; r < 4; ++r) {
                int k = 16 * ct + 4 * lg + r;
                int kc = min(k, 49);
                mbb[ct][r] = mT[kc * 65 + qcol] + bf2f(biasTh[kc * NT + qcol]);
            }

        f32x4 sacc[4];
#pragma unroll
        for (int ct = 0; ct < 4; ++ct) {
            f32x4 z = {0.f, 0.f, 0.f, 0.f};
            sacc[ct] = __builtin_amdgcn_mfma_f32_16x16x32_bf16(kb[ct], qa[mt2], z, 0, 0, 0);
        }

        float e[4][4];
        float psum = 0.f;
#pragma unroll
        for (int ct = 0; ct < 4; ++ct)
#pragma unroll
            for (int r = 0; r < 4; ++r) {
                float ee = exp2f(sacc[ct][r] + mbb[ct][r]);
                if (ct == 3) ee = (r == 0 && lg == 0) ? ee : 0.f;
                e[ct][r] = ee;
                psum += ee;
            }
        psum += __shfl_xor(psum, 16);
        psum += __shfl_xor(psum, 32);
        const float inv = 1.0f / psum;

        unsigned A0 = pk2(e[0][0] * inv, e[0][1] * inv);
        unsigned A1 = pk2(e[1][0] * inv, e[1][1] * inv);
        unsigned A2 = pk2(e[2][0] * inv, e[2][1] * inv);
        unsigned A3 = pk2(e[3][0] * inv, e[3][1] * inv);
        unsigned B0 = pk2(e[0][2] * inv, e[0][3] * inv);
        unsigned B1 = pk2(e[1][2] * inv, e[1][3] * inv);
        unsigned B2 = pk2(e[2][2] * inv, e[2][3] * inv);
        unsigned B3 = pk2(e[3][2] * inv, e[3][3] * inv);
        pl32swap(A0, A2); pl32swap(A1, A3);
        pl16swap(A0, A1); pl16swap(A2, A3);
        pl32swap(B0, B2); pl32swap(B1, B3);
        pl16swap(B0, B1); pl16swap(B2, B3);
        union { unsigned u[4]; bf16x8 v; } p0, p1;
        p0.u[0] = A0; p0.u[1] = B0; p0.u[2] = A1; p0.u[3] = B1;
        p1.u[0] = A2; p1.u[1] = B2; p1.u[2] = A3; p1.u[3] = B3;

#pragma unroll
        for (int nt = 0; nt < 2; ++nt) {
            bf16x8 vb0 = *reinterpret_cast<const bf16x8*>(&vSs[(16 * nt + lr) * 64 + ((8 * lg) ^ sw8)]);
            bf16x8 vb1 = *reinterpret_cast<const bf16x8*>(&vSs[(16 * nt + lr) * 64 + ((32 + 8 * lg) ^ sw8)]);
            oacc[mt2][nt] = __builtin_amdgcn_mfma_f32_16x16x32_bf16(p0.v, vb0, oacc[mt2][nt], 0, 0, 0);
            oacc[mt2][nt] = __builtin_amdgcn_mfma_f32_16x16x32_bf16(p1.v, vb1, oacc[mt2][nt], 0, 0, 0);
        }
    }

    // ---- write o tile into k-plane region (dead after B2) ----
#pragma unroll
    for (int mt2 = 0; mt2 < 2; ++mt2)
#pragma unroll
        for (int nt = 0; nt < 2; ++nt)
#pragma unroll
            for (int r = 0; r < 4; ++r) {
                int row = 16 * (mt0 + mt2) + 4 * lg + r;
                int col = 32 * h + 16 * nt + lr;
                oS[swz128(row, col)] = f2bf(oacc[mt2][nt][r]);
            }
    __syncthreads();   // B3: o ready

    // ================= P3: proj (wave w -> col-tile w) =================
    {
        bf16x8 bbf[4];
        const short* brow = projwT + (w * 16 + lr) * 128 + lg * 8;
#pragma unroll
        for (int kt = 0; kt < 4; ++kt)
            bbf[kt] = *reinterpret_cast<const bf16x8*>(brow + kt * 32);

        f32x4 acc[4];
#pragma unroll
        for (int mf = 0; mf < 4; ++mf) acc[mf] = f32x4{0.f, 0.f, 0.f, 0.f};

#pragma unroll
        for (int mf = 0; mf < 4; ++mf)
#pragma unroll
            for (int kt = 0; kt < 4; ++kt) {
                bf16x8 a2 = *reinterpret_cast<const bf16x8*>(&oS[swz128(16 * mf + lr, kt * 32 + lg * 8)]);
                acc[mf] = __builtin_amdgcn_mfma_f32_16x16x32_bf16(a2, bbf[kt], acc[mf], 0, 0, 0);
            }

        const int col = w * 16 + lr;
        const float pb = proj_b[col];
#pragma unroll
        for (int mf = 0; mf < 4; ++mf)
#pragma unroll
            for (int r = 0; r < 4; ++r) {
                int row = 16 * mf + 4 * lg + r;
                if (row < NT)
                    out[((size_t)b * NT + row) * CD + col] = acc[mf][r] + pb;
            }
    }
}

extern "C" void kernel_launch(void* const* d_in, const int* in_sizes, int n_in,
                              void* d_out, int out_size, void* d_ws, size_t ws_size,
                              hipStream_t stream) {
    const float* x      = (const float*)d_in[0];
    const float* mask   = (const float*)d_in[1];
    const float* qkv_w  = (const float*)d_in[2];
    const float* qkv_b  = (const float*)d_in[3];
    const float* rbt    = (const float*)d_in[4];
    const float* proj_w = (const float*)d_in[5];
    const float* proj_b = (const float*)d_in[6];
    const int*   ridx   = (const int*)d_in[7];
    float* out = (float*)d_out;

    char* ws = (char*)d_ws;
    short* qkvwS  = (short*)(ws + WS_QKVWS);
    short* projwT = (short*)(ws + WS_PROJWT);
    unsigned short* biasBf = (unsigned short*)(ws + WS_BIAS);

    prep_kernel<<<192, 256, 0, stream>>>(qkv_w, proj_w, rbt, ridx, qkvwS, projwT, biasBf);
    fused_kernel<<<NB, 512, 0, stream>>>(x, mask, qkv_b, qkvwS, biasBf, projwT, proj_b, out);
}

// Round 17
// 291.509 us; speedup vs baseline: 1.5192x; 1.0038x over previous
//
#include <hip/hip_runtime.h>
#include <hip/hip_bf16.h>

using f32x4 = __attribute__((ext_vector_type(4))) float;
using bf16x8 = __attribute__((ext_vector_type(8))) short;

#define DEVI __device__ __forceinline__

DEVI short f2bf(float f) { __hip_bfloat16 h = __float2bfloat16(f); return *reinterpret_cast<short*>(&h); }
DEVI unsigned int pk2(float a, float b) {
    float2 t; t.x = a; t.y = b;
    __hip_bfloat162 h = __float22bfloat162_rn(t);
    return *reinterpret_cast<unsigned int*>(&h);
}
DEVI float bf2f(unsigned short s) { unsigned int u = ((unsigned int)s) << 16; return __uint_as_float(u); }

DEVI void pl32swap(unsigned& a, unsigned& b) { asm("v_permlane32_swap_b32 %0, %1" : "+v"(a), "+v"(b)); }
DEVI void pl16swap(unsigned& a, unsigned& b) { asm("v_permlane16_swap_b32 %0, %1" : "+v"(a), "+v"(b)); }

#define GLOAD_LDS16(gp, lp) \
    __builtin_amdgcn_global_load_lds((const __attribute__((address_space(1))) void*)(gp), \
                                     (__attribute__((address_space(3))) void*)(lp), 16, 0, 0)

constexpr int NB = 8192;
constexpr int NT = 49;
constexpr int CD = 128;
constexpr float SCALE = 0.17677669529663687f;
constexpr float LOG2E = 1.4426950408889634f;

// ---- ws layout (bytes) ----
constexpr size_t WS_QKVWS  = 0;        // 384*128 bf16, chunked + pre-swizzled
constexpr size_t WS_PROJWT = 98304;    // 128*128 bf16 [n][k] plain transposed
constexpr size_t WS_BIAS   = 131072;   // 4*2401 bf16 transposed [h][k][q] x LOG2E

DEVI void div49(unsigned grow, unsigned& bI, unsigned& tI) {
    bI = (unsigned)(((unsigned long long)grow * 2804876602ull) >> 37);
    tI = grow - bI * 49u;
}

DEVI int swz128(int row, int col) { return row * 128 + (col ^ ((row & 7) << 3)); }

// ============================================================================
// prep: qkv weights chunked [c][r][j^((r&7)<<3)] pre-swizzled (for gload_lds
// + XOR ds_read); proj weights plain-transposed; bias [h][k][q] x LOG2E.
// ============================================================================
__global__ __launch_bounds__(256) void prep_kernel(
    const float* __restrict__ qkv_w, const float* __restrict__ proj_w,
    const float* __restrict__ rbt, const int* __restrict__ rel_index,
    short* __restrict__ qkvwS, short* __restrict__ projwT, unsigned short* __restrict__ biasBf)
{
    int i = blockIdx.x * 256 + threadIdx.x;
    if (i < 384 * 128) {
        int n = i >> 7, j = i & 127;          // B[n][k=j]
        int c = n >> 7, r = n & 127;
        qkvwS[c * 16384 + r * 128 + (j ^ ((r & 7) << 3))] = f2bf(qkv_w[j * 384 + n]);
    }
    if (i < 128 * 128) {
        int n = i >> 7, j = i & 127;
        projwT[n * 128 + j] = f2bf(proj_w[j * 128 + n]);
    }
    if (i < 4 * NT * NT) {
        int h = i / (NT * NT); int t = i % (NT * NT);
        int k = t / NT, q = t - k * NT;
        biasBf[i] = (unsigned short)f2bf(rbt[rel_index[q * NT + k] * 4 + h] * LOG2E);
    }
}

// ============================================================================
// FUSED kernel: block = 1 window (512 thr, 8 waves). LDS 80 KB.
//   Wc  [0,32768)        weight chunk, DMA-staged; mT aliases after P1
//   qk  [32768,65536)    q plane then k plane, [4 h][64 t][32 d],
//                        slot-XOR: gp = (d>>2) ^ (t&6) ^ ((t&8)>>1)
//   vS  [65536,81920)    [4 h][32 d][64 slots] slot-permuted + XOR
//   oS aliases k-plane after B2.
// R17 deltas vs R16: (1) qk swizzle +t&8 bit (write conflicts 4->2-way);
// (2) bias prefetched to regs post-B1 (hides under B2); (3) proj B-frags
// loaded before oS writes (hides under o-stores + B3).
// ============================================================================
__global__ __launch_bounds__(512, 4) void fused_kernel(
    const float* __restrict__ x, const float* __restrict__ mask,
    const float* __restrict__ qkv_b, const short* __restrict__ qkvwS,
    const unsigned short* __restrict__ biasT, const short* __restrict__ projwT,
    const float* __restrict__ proj_b, float* __restrict__ out)
{
    __shared__ __attribute__((aligned(16))) short pool[40960];   // 81920 B
    char*  Wcb = (char*)pool;                  // [0, 32768)
    char*  qkb = (char*)pool + 32768;          // q [32768,49152), k [49152,65536)
    char*  vSb = (char*)pool + 65536;          // [65536, 81920)
    float* mT  = (float*)pool;                 // aliases Wc (after P1)
    short* oS  = (short*)((char*)pool + 49152);// aliases k plane (after B2)

    const int b = blockIdx.x;
    const int tid = threadIdx.x;
    const int w = tid >> 6, lane = tid & 63, lr = lane & 15, lg = lane >> 4;
    const int h = w >> 1, half = w & 1;
    const int wpair = w >> 1;            // n-tile selector 0..3
    const int tsel = w & 1;              // token-pair selector

    // ---- mask prefetch to regs (independent; hides under P1) ----
    const float* mb_ = mask + (size_t)b * (NT * NT);
    float mreg[5];
#pragma unroll
    for (int ii = 0; ii < 5; ++ii) {
        int i = tid + ii * 512;
        mreg[ii] = (i < NT * NT) ? mb_[i] * LOG2E : 0.f;
    }

    // ---- x fragments: wave covers token-tiles {2*tsel, 2*tsel+1} ----
    bf16x8 af[2][4];
#pragma unroll
    for (int mf = 0; mf < 2; ++mf) {
        const int row = 32 * tsel + 16 * mf + lr;
        const bool valid = row < NT;
        const float* xrow = x + ((size_t)b * NT + (valid ? row : 0)) * CD;
#pragma unroll
        for (int kt = 0; kt < 4; ++kt) {
            float4 v0 = {0.f,0.f,0.f,0.f}, v1 = {0.f,0.f,0.f,0.f};
            if (valid) {
                const float4* p = reinterpret_cast<const float4*>(xrow + kt * 32 + lg * 8);
                v0 = p[0]; v1 = p[1];
            }
            union { unsigned int u[4]; bf16x8 v; } cv;
            cv.u[0] = pk2(v0.x, v0.y); cv.u[1] = pk2(v0.z, v0.w);
            cv.u[2] = pk2(v1.x, v1.y); cv.u[3] = pk2(v1.z, v1.w);
            af[mf][kt] = cv.v;
        }
    }

    // ================= P1: QKV GEMM, weights DMA-staged per chunk =================
    const char* srcW = (const char*)qkvwS;
#pragma unroll
    for (int c = 0; c < 3; ++c) {
        // stage chunk c (32KB): 8 waves x 4 x 1KB
#pragma unroll
        for (int i = 0; i < 4; ++i)
            GLOAD_LDS16(srcW + c * 32768 + w * 4096 + i * 1024 + lane * 16,
                        Wcb + w * 4096 + i * 1024);
        __syncthreads();

        if (c < 2) {
            // q (c=0) / k (c=1): SWAPPED mfma(W, x) -> [token=lr][d=4lg+r] -> b64
#pragma unroll
            for (int nn = 0; nn < 2; ++nn) {
                const int ntl = wpair + 4 * nn;
                const int nt = c * 8 + ntl;
                const int hh = (ntl >> 1) & 3;
                const int dtile = ntl & 1;
                const float4 b4 = *reinterpret_cast<const float4*>(qkv_b + nt * 16 + 4 * lg);
                const float scl = (c == 0) ? SCALE * LOG2E : 1.0f;
                const char* wbase = Wcb + (ntl * 16 + lr) * 256;
                const int wsw = (lr & 7) << 4;
#pragma unroll
                for (int tf = 0; tf < 2; ++tf) {
                    f32x4 acc = {0.f, 0.f, 0.f, 0.f};
#pragma unroll
                    for (int kt = 0; kt < 4; ++kt) {
                        bf16x8 wf = *reinterpret_cast<const bf16x8*>(wbase + ((kt * 64 + lg * 16) ^ wsw));
                        acc = __builtin_amdgcn_mfma_f32_16x16x32_bf16(wf, af[tf][kt], acc, 0, 0, 0);
                    }
                    const int t = 16 * (2 * tsel + tf) + lr;
                    const int gp = (dtile * 4 + lg) ^ (t & 6) ^ ((t & 8) >> 1);
                    uint2 s;
                    s.x = pk2((acc[0] + b4.x) * scl, (acc[1] + b4.y) * scl);
                    s.y = pk2((acc[2] + b4.z) * scl, (acc[3] + b4.w) * scl);
                    *reinterpret_cast<uint2*>(qkb + c * 16384 + hh * 4096 + t * 64 + gp * 8) = s;
                }
            }
        } else {
            // v: non-swapped mfma(x, W) -> [d=d0+lr][4 consecutive slot tokens] -> b64
#pragma unroll
            for (int nn = 0; nn < 2; ++nn) {
                const int ntl = wpair + 4 * nn;
                const int nt = 16 + ntl;
                const int hh = (ntl >> 1) & 3;
                const int d0 = (ntl & 1) * 16;
                const float bv = qkv_b[nt * 16 + lr];
                const int d = d0 + lr;
                const char* wbase = Wcb + (ntl * 16 + lr) * 256;
                const int wsw = (lr & 7) << 4;
#pragma unroll
                for (int tf = 0; tf < 2; ++tf) {
                    f32x4 acc = {0.f, 0.f, 0.f, 0.f};
#pragma unroll
                    for (int kt = 0; kt < 4; ++kt) {
                        bf16x8 wf = *reinterpret_cast<const bf16x8*>(wbase + ((kt * 64 + lg * 16) ^ wsw));
                        acc = __builtin_amdgcn_mfma_f32_16x16x32_bf16(af[tf][kt], wf, acc, 0, 0, 0);
                    }
                    const int tt = 2 * tsel + tf;
                    const int slotq = (lg < 2) ? (tt * 8 + 4 * lg) : (24 + tt * 8 + 4 * lg);
                    const int gp = (slotq >> 2) ^ ((d & 7) << 1);
                    uint2 s;
                    s.x = pk2(acc[0] + bv, acc[1] + bv);
                    s.y = pk2(acc[2] + bv, acc[3] + bv);
                    *reinterpret_cast<uint2*>(vSb + hh * 4096 + d * 128 + gp * 8) = s;
                }
            }
        }
        __syncthreads();   // chunk reads done before restage; c==2: B1 (q/k/v visible, Wc dead)
    }

    // ================= P2a: q/k frag loads + bias prefetch + mask scatter =======
    const int mt0 = 2 * half;
    const unsigned short* biasTh = biasT + h * (NT * NT);
    bf16x8 qa[2], kb[4];
#pragma unroll
    for (int i = 0; i < 2; ++i) {
        const int t = 16 * (mt0 + i) + lr;
        qa[i] = *reinterpret_cast<const bf16x8*>(
            qkb + h * 4096 + t * 64 + ((16 * lg) ^ ((t & 6) << 3) ^ ((t & 8) << 2)));
    }
#pragma unroll
    for (int t4 = 0; t4 < 4; ++t4) {
        const int t = 16 * t4 + lr;
        kb[t4] = *reinterpret_cast<const bf16x8*>(
            qkb + 16384 + h * 4096 + t * 64 + ((16 * lg) ^ ((t & 6) << 3) ^ ((t & 8) << 2)));
    }
    // bias prefetch (global, independent of LDS; hides under B2 barrier wait)
    unsigned short braw[2][4][4];
#pragma unroll
    for (int mt2 = 0; mt2 < 2; ++mt2) {
        const int qcol = 16 * (mt0 + mt2) + lr;
#pragma unroll
        for (int ct = 0; ct < 4; ++ct)
#pragma unroll
            for (int r = 0; r < 4; ++r) {
                int k = 16 * ct + 4 * lg + r;
                int kc = min(k, 49);
                braw[mt2][ct][r] = biasTh[kc * NT + qcol];
            }
    }
    // scatter mask regs -> mT transposed (Wc region, dead after B1)
#pragma unroll
    for (int ii = 0; ii < 5; ++ii) {
        int i = tid + ii * 512;
        if (i < NT * NT) {
            unsigned q_, k_;
            div49((unsigned)i, q_, k_);
            mT[k_ * 65 + q_] = mreg[ii];
        }
    }
    __syncthreads();   // B2: mT visible; all q/k frag reads done (k plane -> oS)

    // ================= P2b: attn =================
    const short* vSs = (short*)vSb + h * 2048;
    const int sw8 = (lr & 7) << 3;

    f32x4 oacc[2][2];
#pragma unroll
    for (int mt2 = 0; mt2 < 2; ++mt2) { oacc[mt2][0] = f32x4{0,0,0,0}; oacc[mt2][1] = f32x4{0,0,0,0}; }

#pragma unroll
    for (int mt2 = 0; mt2 < 2; ++mt2) {
        const int qcol = 16 * (mt0 + mt2) + lr;

        float mbb[4][4];
#pragma unroll
        for (int ct = 0; ct < 4; ++ct)
#pragma unroll
            for (int r = 0; r < 4; ++r) {
                int k = 16 * ct + 4 * lg + r;
                int kc = min(k, 49);
                mbb[ct][r] = mT[kc * 65 + qcol] + bf2f(braw[mt2][ct][r]);
            }

        f32x4 sacc[4];
#pragma unroll
        for (int ct = 0; ct < 4; ++ct) {
            f32x4 z = {0.f, 0.f, 0.f, 0.f};
            sacc[ct] = __builtin_amdgcn_mfma_f32_16x16x32_bf16(kb[ct], qa[mt2], z, 0, 0, 0);
        }

        float e[4][4];
        float psum = 0.f;
#pragma unroll
        for (int ct = 0; ct < 4; ++ct)
#pragma unroll
            for (int r = 0; r < 4; ++r) {
                float ee = exp2f(sacc[ct][r] + mbb[ct][r]);
                if (ct == 3) ee = (r == 0 && lg == 0) ? ee : 0.f;
                e[ct][r] = ee;
                psum += ee;
            }
        psum += __shfl_xor(psum, 16);
        psum += __shfl_xor(psum, 32);
        const float inv = 1.0f / psum;

        unsigned A0 = pk2(e[0][0] * inv, e[0][1] * inv);
        unsigned A1 = pk2(e[1][0] * inv, e[1][1] * inv);
        unsigned A2 = pk2(e[2][0] * inv, e[2][1] * inv);
        unsigned A3 = pk2(e[3][0] * inv, e[3][1] * inv);
        unsigned B0 = pk2(e[0][2] * inv, e[0][3] * inv);
        unsigned B1 = pk2(e[1][2] * inv, e[1][3] * inv);
        unsigned B2 = pk2(e[2][2] * inv, e[2][3] * inv);
        unsigned B3 = pk2(e[3][2] * inv, e[3][3] * inv);
        pl32swap(A0, A2); pl32swap(A1, A3);
        pl16swap(A0, A1); pl16swap(A2, A3);
        pl32swap(B0, B2); pl32swap(B1, B3);
        pl16swap(B0, B1); pl16swap(B2, B3);
        union { unsigned u[4]; bf16x8 v; } p0, p1;
        p0.u[0] = A0; p0.u[1] = B0; p0.u[2] = A1; p0.u[3] = B1;
        p1.u[0] = A2; p1.u[1] = B2; p1.u[2] = A3; p1.u[3] = B3;

#pragma unroll
        for (int nt = 0; nt < 2; ++nt) {
            bf16x8 vb0 = *reinterpret_cast<const bf16x8*>(&vSs[(16 * nt + lr) * 64 + ((8 * lg) ^ sw8)]);
            bf16x8 vb1 = *reinterpret_cast<const bf16x8*>(&vSs[(16 * nt + lr) * 64 + ((32 + 8 * lg) ^ sw8)]);
            oacc[mt2][nt] = __builtin_amdgcn_mfma_f32_16x16x32_bf16(p0.v, vb0, oacc[mt2][nt], 0, 0, 0);
            oacc[mt2][nt] = __builtin_amdgcn_mfma_f32_16x16x32_bf16(p1.v, vb1, oacc[mt2][nt], 0, 0, 0);
        }
    }

    // ---- proj B-frag prefetch (independent; hides under o-stores + B3) ----
    bf16x8 bbf[4];
    {
        const short* brow = projwT + (w * 16 + lr) * 128 + lg * 8;
#pragma unroll
        for (int kt = 0; kt < 4; ++kt)
            bbf[kt] = *reinterpret_cast<const bf16x8*>(brow + kt * 32);
    }

    // ---- write o tile into k-plane region (dead after B2) ----
#pragma unroll
    for (int mt2 = 0; mt2 < 2; ++mt2)
#pragma unroll
        for (int nt = 0; nt < 2; ++nt)
#pragma unroll
            for (int r = 0; r < 4; ++r) {
                int row = 16 * (mt0 + mt2) + 4 * lg + r;
                int col = 32 * h + 16 * nt + lr;
                oS[swz128(row, col)] = f2bf(oacc[mt2][nt][r]);
            }
    __syncthreads();   // B3: o ready

    // ================= P3: proj (wave w -> col-tile w) =================
    {
        f32x4 acc[4];
#pragma unroll
        for (int mf = 0; mf < 4; ++mf) acc[mf] = f32x4{0.f, 0.f, 0.f, 0.f};

#pragma unroll
        for (int mf = 0; mf < 4; ++mf)
#pragma unroll
            for (int kt = 0; kt < 4; ++kt) {
                bf16x8 a2 = *reinterpret_cast<const bf16x8*>(&oS[swz128(16 * mf + lr, kt * 32 + lg * 8)]);
                acc[mf] = __builtin_amdgcn_mfma_f32_16x16x32_bf16(a2, bbf[kt], acc[mf], 0, 0, 0);
            }

        const int col = w * 16 + lr;
        const float pb = proj_b[col];
#pragma unroll
        for (int mf = 0; mf < 4; ++mf)
#pragma unroll
            for (int r = 0; r < 4; ++r) {
                int row = 16 * mf + 4 * lg + r;
                if (row < NT)
                    out[((size_t)b * NT + row) * CD + col] = acc[mf][r] + pb;
            }
    }
}

extern "C" void kernel_launch(void* const* d_in, const int* in_sizes, int n_in,
                              void* d_out, int out_size, void* d_ws, size_t ws_size,
                              hipStream_t stream) {
    const float* x      = (const float*)d_in[0];
    const float* mask   = (const float*)d_in[1];
    const float* qkv_w  = (const float*)d_in[2];
    const float* qkv_b  = (const float*)d_in[3];
    const float* rbt    = (const float*)d_in[4];
    const float* proj_w = (const float*)d_in[5];
    const float* proj_b = (const float*)d_in[6];
    const int*   ridx   = (const int*)d_in[7];
    float* out = (float*)d_out;

    char* ws = (char*)d_ws;
    short* qkvwS  = (short*)(ws + WS_QKVWS);
    short* projwT = (short*)(ws + WS_PROJWT);
    unsigned short* biasBf = (unsigned short*)(ws + WS_BIAS);

    prep_kernel<<<192, 256, 0, stream>>>(qkv_w, proj_w, rbt, ridx, qkvwS, projwT, biasBf);
    fused_kernel<<<NB, 512, 0, stream>>>(x, mask, qkv_b, qkvwS, biasBf, projwT, proj_b, out);
}